// Round 5
// baseline (2448.158 us; speedup 1.0000x reference)
//
#include <hip/hip_runtime.h>
#include <hip/hip_bf16.h>

typedef __attribute__((ext_vector_type(8))) short short8;
typedef __attribute__((ext_vector_type(4))) float floatx4;

__device__ __forceinline__ unsigned short f2bf(float x) {
  __hip_bfloat16 h = __float2bfloat16(x);
  return __builtin_bit_cast(unsigned short, h);
}

// ---------------------------------------------------------------------
// Build extended transposed weights: Bt[o][r], r = k*64+d for k<K2 (from
// W[k][d][o]), and r in [K2*64, K2*64+64) from root[d][o]. bf16.
// ---------------------------------------------------------------------
__global__ __launch_bounds__(256) void cvt_wext_kernel(
    const float* __restrict__ W, const float* __restrict__ root,
    unsigned short* __restrict__ Bt, int K2) {
  int R = (K2 + 1) * 64;
  int i = blockIdx.x * 256 + threadIdx.x;
  if (i >= 64 * R) return;
  int o = i / R, r = i - o * R;
  int k = r >> 6, d = r & 63;
  float v = (k < K2) ? W[(k << 12) + (d << 6) + o] : root[(d << 6) + o];
  Bt[(size_t)o * R + r] = f2bf(v);
}

// ---------------------------------------------------------------------
// CSR build: histogram -> scan -> cursor scatter
// ---------------------------------------------------------------------
__global__ __launch_bounds__(256) void zero_int_kernel(int* __restrict__ p, int n) {
  int i = blockIdx.x * 256 + threadIdx.x;
  if (i < n) p[i] = 0;
}

__global__ __launch_bounds__(256) void hist_kernel(
    const int* __restrict__ dst, int* __restrict__ deg, int nE) {
  int e = blockIdx.x * 256 + threadIdx.x;
  if (e < nE) atomicAdd(&deg[dst[e]], 1);
}

__global__ __launch_bounds__(256) void blocksum_kernel(
    const int* __restrict__ deg, int* __restrict__ partial, int N) {
  __shared__ int s[256];
  int t = threadIdx.x, i = blockIdx.x * 256 + t;
  s[t] = (i < N) ? deg[i] : 0;
  __syncthreads();
  for (int off = 128; off > 0; off >>= 1) {
    if (t < off) s[t] += s[t + off];
    __syncthreads();
  }
  if (t == 0) partial[blockIdx.x] = s[0];
}

// single-block exclusive scan of up to 256 partials (N <= 65536)
__global__ __launch_bounds__(256) void scanpartials_kernel(
    int* __restrict__ partial, int nb) {
  __shared__ int s[256];
  int t = threadIdx.x;
  int v = (t < nb) ? partial[t] : 0;
  s[t] = v;
  __syncthreads();
  for (int off = 1; off < 256; off <<= 1) {
    int x = (t >= off) ? s[t - off] : 0;
    __syncthreads();
    s[t] += x;
    __syncthreads();
  }
  if (t < nb) partial[t] = s[t] - v;
}

__global__ __launch_bounds__(256) void blockscan_kernel(
    const int* __restrict__ deg, const int* __restrict__ partial,
    int* __restrict__ row_start, int* __restrict__ cursor, int N, int nE) {
  __shared__ int s[256];
  int t = threadIdx.x, i = blockIdx.x * 256 + t;
  int v = (i < N) ? deg[i] : 0;
  s[t] = v;
  __syncthreads();
  for (int off = 1; off < 256; off <<= 1) {
    int x = (t >= off) ? s[t - off] : 0;
    __syncthreads();
    s[t] += x;
    __syncthreads();
  }
  if (i < N) {
    int excl = s[t] - v + partial[blockIdx.x];
    row_start[i] = excl;
    cursor[i] = excl;
  }
  if (i == 0) row_start[N] = nE;
}

__global__ __launch_bounds__(256) void scatter_kernel(
    const int* __restrict__ dst, int* __restrict__ cursor,
    int* __restrict__ eidx, int nE) {
  int e = blockIdx.x * 256 + threadIdx.x;
  if (e < nE) {
    int pos = atomicAdd(&cursor[dst[e]], 1);
    eidx[pos] = e;
  }
}

// ---------------------------------------------------------------------
// Z-build: one wave per dst node. Zext[n] = [ (1/deg)*bucketed x-sums , x[n] ]
// LDS bucket accum (lane = channel, ds_add_f32, no races); edge metadata
// prefetched 64-at-a-time by parallel lanes; x-gather pipelined 1 ahead.
// ---------------------------------------------------------------------
template <int K, int K2>
__global__ __launch_bounds__(256) void zbuild_kernel(
    const int* __restrict__ eidx, const int* __restrict__ row_start,
    const int* __restrict__ src, const float* __restrict__ attr,
    const float* __restrict__ X, unsigned short* __restrict__ Z, int N) {
  constexpr int R = (K2 + 1) * 64;
  __shared__ float Zacc[4][K2 * 64];
  __shared__ float metaB[4][64][4];
  __shared__ int metaS[4][64];
  __shared__ int metaK[4][64];
  const int t = threadIdx.x, w = t >> 6, o = t & 63;
  const int node = blockIdx.x * 4 + w;
  if (node >= N) return;  // no __syncthreads anywhere in this kernel

  float* za = Zacc[w];
#pragma unroll
  for (int k = 0; k < K2; ++k) za[k * 64 + o] = 0.f;

  const int beg = row_start[node], end = row_start[node + 1];
  for (int c0 = beg; c0 < end; c0 += 64) {
    const int m = min(64, end - c0);
    if (o < m) {
      int e = eidx[c0 + o];
      float2 a = *(const float2*)&attr[2 * e];
      int s = src[e];
      float u = a.x * (float)(K - 1);
      float v = a.y * (float)(K - 1);
      float lf0 = floorf(u), lf1 = floorf(v);
      float f0 = u - lf0, f1 = v - lf1;
      int l0 = (int)lf0, l1 = (int)lf1;
      int i00 = min(max(l0, 0), K - 1), i01 = min(max(l0 + 1, 0), K - 1);
      int i10 = min(max(l1, 0), K - 1), i11 = min(max(l1 + 1, 0), K - 1);
      metaB[w][o][0] = (1.f - f0) * (1.f - f1);
      metaB[w][o][1] = (1.f - f0) * f1;
      metaB[w][o][2] = f0 * (1.f - f1);
      metaB[w][o][3] = f0 * f1;
      metaS[w][o] = s;
      metaK[w][o] = (i00 + i10 * K) | ((i00 + i11 * K) << 8) |
                    ((i01 + i10 * K) << 16) | ((i01 + i11 * K) << 24);
    }
    // same-wave LDS write->read: lockstep + compiler waitcnts
    int s0 = metaS[w][0];
    float xv = X[(size_t)s0 * 64 + o];
    for (int j = 0; j < m; ++j) {
      float xn = 0.f;
      if (j + 1 < m) {
        int sn = metaS[w][j + 1];
        xn = X[(size_t)sn * 64 + o];
      }
      int kp = metaK[w][j];
      float4 b = *(const float4*)&metaB[w][j][0];
      atomicAdd(&za[(kp & 255) * 64 + o], b.x * xv);
      atomicAdd(&za[((kp >> 8) & 255) * 64 + o], b.y * xv);
      atomicAdd(&za[((kp >> 16) & 255) * 64 + o], b.z * xv);
      atomicAdd(&za[((kp >> 24) & 255) * 64 + o], b.w * xv);
      xv = xn;
    }
  }

  const int deg = end - beg;
  const float inv = 1.f / (float)max(deg, 1);
  unsigned short* zr = Z + (size_t)node * R;
#pragma unroll
  for (int k = 0; k < K2; ++k) zr[k * 64 + o] = f2bf(za[k * 64 + o] * inv);
  zr[K2 * 64 + o] = f2bf(X[(size_t)node * 64 + o]);
}

// ---------------------------------------------------------------------
// Fused GEMM: out[n,o] = ELU( Zext[n,:] @ Bt[o,:] + bias[o] )  (bf16 MFMA)
// Zext row-major [N x R], Bt row-major [64 x R], R = KC*64.
// Block 256 (4 waves), 64 nodes/block; k-loop over KC 64-chunks.
// ---------------------------------------------------------------------
template <int KC>
__global__ __launch_bounds__(256) void gemm_fused_kernel(
    const unsigned short* __restrict__ Z, const unsigned short* __restrict__ Bt,
    const float* __restrict__ bias, float* __restrict__ out, int N) {
  constexpr int R = KC * 64;
  __shared__ unsigned short As[64 * 72];
  __shared__ unsigned short Bs[64 * 72];
  const int t = threadIdx.x, w = t >> 6, lane = t & 63;
  const int mrow = lane & 15, q = lane >> 4;
  const int n0 = blockIdx.x * 64;

  floatx4 acc[4] = {{0,0,0,0},{0,0,0,0},{0,0,0,0},{0,0,0,0}};

  for (int kc = 0; kc < KC; ++kc) {
    __syncthreads();
    for (int i = t; i < 512; i += 256) {
      int row = i >> 3, cg = i & 7;
      int n = n0 + row;
      float4 val = make_float4(0.f, 0.f, 0.f, 0.f);
      if (n < N) val = *(const float4*)&Z[(size_t)n * R + kc * 64 + cg * 8];
      *(float4*)&As[row * 72 + cg * 8] = val;
    }
    for (int i = t; i < 512; i += 256) {
      int row = i >> 3, cg = i & 7;
      *(float4*)&Bs[row * 72 + cg * 8] =
          *(const float4*)&Bt[(size_t)row * R + kc * 64 + cg * 8];
    }
    __syncthreads();

    short8 a0 = *(const short8*)&As[(w * 16 + mrow) * 72 + q * 8];
    short8 a1 = *(const short8*)&As[(w * 16 + mrow) * 72 + 32 + q * 8];
#pragma unroll
    for (int ot = 0; ot < 4; ++ot) {
      short8 b0 = *(const short8*)&Bs[(ot * 16 + mrow) * 72 + q * 8];
      short8 b1 = *(const short8*)&Bs[(ot * 16 + mrow) * 72 + 32 + q * 8];
      acc[ot] = __builtin_amdgcn_mfma_f32_16x16x32_bf16(a0, b0, acc[ot], 0, 0, 0);
      acc[ot] = __builtin_amdgcn_mfma_f32_16x16x32_bf16(a1, b1, acc[ot], 0, 0, 0);
    }
  }

  // epilogue: D layout col(o)=ot*16+mrow, row(node)=q*4+r
#pragma unroll
  for (int ot = 0; ot < 4; ++ot) {
    float b = bias[ot * 16 + mrow];
#pragma unroll
    for (int r = 0; r < 4; ++r) {
      int node = n0 + w * 16 + q * 4 + r;
      if (node < N) {
        float v = acc[ot][r] + b;
        v = v > 0.f ? v : (expf(v) - 1.f);
        out[(size_t)node * 64 + ot * 16 + mrow] = v;
      }
    }
  }
}

// ---------------------------------------------------------------------
// dense layer (fp32 VALU): out = act(X@Wm + b); ACT 1=ReLU
// ---------------------------------------------------------------------
template <int ACT>
__global__ __launch_bounds__(256) void node_dense_kernel(
    const float* __restrict__ X, const float* __restrict__ Wm,
    const float* __restrict__ bias, float* __restrict__ out, int N) {
  __shared__ float Ws[64 * 64];
  __shared__ float XsT[64 * 132];
  const int t = threadIdx.x;
  const int n0 = blockIdx.x * 128;

  for (int i = t; i < 1024; i += 256)
    ((float4*)Ws)[i] = ((const float4*)Wm)[i];
  for (int i = t; i < 8192; i += 256) {
    int nl = i >> 6, d = i & 63;
    int n = n0 + nl;
    XsT[d * 132 + nl] = (n < N) ? X[(size_t)n * 64 + d] : 0.f;
  }
  __syncthreads();

  const int o = t & 63, ng = t >> 6;
  float acc[32];
#pragma unroll
  for (int j = 0; j < 32; ++j) acc[j] = 0.f;

  for (int d = 0; d < 64; ++d) {
    float w = Ws[d * 64 + o];
    const float4* xp = (const float4*)&XsT[d * 132 + ng * 32];
#pragma unroll
    for (int j4 = 0; j4 < 8; ++j4) {
      float4 xv = xp[j4];
      acc[j4 * 4 + 0] += xv.x * w;
      acc[j4 * 4 + 1] += xv.y * w;
      acc[j4 * 4 + 2] += xv.z * w;
      acc[j4 * 4 + 3] += xv.w * w;
    }
  }

  float b = bias[o];
#pragma unroll
  for (int j = 0; j < 32; ++j) {
    int n = n0 + ng * 32 + j;
    if (n >= N) continue;
    float v = acc[j] + b;
    if (ACT == 0) v = v > 0.f ? v : (expf(v) - 1.f);
    else          v = v > 0.f ? v : 0.f;
    out[(size_t)n * 64 + o] = v;
  }
}

// ---------------------------------------------------------------------
// final projection D=64 -> C=8 with ReLU
// ---------------------------------------------------------------------
__global__ __launch_bounds__(256) void mlp2_kernel(
    const float* __restrict__ X, const float* __restrict__ W,
    const float* __restrict__ bias, float* __restrict__ out, int N) {
  __shared__ float Ws[512];
  __shared__ float bs[8];
  __shared__ float Xs[32 * 64];
  int t = threadIdx.x;
  int n0 = blockIdx.x * 32;
  if (t < 8) bs[t] = bias[t];
  for (int i = t; i < 512; i += 256) Ws[i] = W[i];
  for (int i = t; i < 512; i += 256) {
    int n = n0 + (i >> 4);
    ((float4*)Xs)[i] = (n < N) ? ((const float4*)(X + (size_t)n * 64))[i & 15]
                               : make_float4(0.f, 0.f, 0.f, 0.f);
  }
  __syncthreads();
  int c = t & 7, nl = t >> 3;
  float acc = bs[c];
  for (int d = 0; d < 64; ++d) acc += Xs[nl * 64 + d] * Ws[d * 8 + c];
  int n = n0 + nl;
  if (n < N) out[(size_t)n * 8 + c] = acc > 0.f ? acc : 0.f;
}

// ---------------------------------------------------------------------
extern "C" void kernel_launch(void* const* d_in, const int* in_sizes, int n_in,
                              void* d_out, int out_size, void* d_ws, size_t ws_size,
                              hipStream_t stream) {
  const float* x     = (const float*)d_in[0];
  const int*   ei    = (const int*)d_in[1];
  const float* attr  = (const float*)d_in[2];
  const float* W1    = (const float*)d_in[3];
  const float* root1 = (const float*)d_in[4];
  const float* b1    = (const float*)d_in[5];
  const float* W2    = (const float*)d_in[6];
  const float* root2 = (const float*)d_in[7];
  const float* b2    = (const float*)d_in[8];
  const float* m1w   = (const float*)d_in[9];
  const float* m1b   = (const float*)d_in[10];
  const float* m2w   = (const float*)d_in[11];
  const float* m2b   = (const float*)d_in[12];

  const int N  = in_sizes[0] / 64;
  const int nE = in_sizes[1] / 2;
  const int* src  = ei;
  const int* dstv = ei + nE;
  float* out = (float*)d_out;

  // workspace layout
  float* h1 = (float*)d_ws;                 // N*64
  float* h2 = h1 + (size_t)N * 64;          // N*64
  float* t1 = h2 + (size_t)N * 64;          // N*64
  int* deg       = (int*)(t1 + (size_t)N * 64);
  int* row_start = deg + N;
  int* cursor    = row_start + (N + 1);
  int* eidx      = cursor + N;
  int* partial   = eidx + nE;               // 256
  char* pbase = (char*)(partial + 256);
  pbase = (char*)(((uintptr_t)pbase + 15) & ~(uintptr_t)15);
  unsigned short* Bt1 = (unsigned short*)pbase;       // 64 * 640
  unsigned short* Bt2 = Bt1 + 64 * 640;               // 64 * 1664
  unsigned short* Z   = Bt2 + 64 * 1664;              // N * 1664

  dim3 blk(256);
  int nbN  = (N + 255) / 256;
  int nbE  = (nE + 255) / 256;
  int nbZ  = (N + 3) / 4;
  int nbG  = (N + 63) / 64;
  int nb128 = (N + 127) / 128;

  // ----- CSR build (graph identical both layers) -----
  zero_int_kernel<<<nbN, blk, 0, stream>>>(deg, N);
  hist_kernel<<<nbE, blk, 0, stream>>>(dstv, deg, nE);
  blocksum_kernel<<<nbN, blk, 0, stream>>>(deg, partial, N);
  scanpartials_kernel<<<1, blk, 0, stream>>>(partial, nbN);
  blockscan_kernel<<<nbN, blk, 0, stream>>>(deg, partial, row_start, cursor, N, nE);
  scatter_kernel<<<nbE, blk, 0, stream>>>(dstv, cursor, eidx, nE);

  // ----- weight prep -----
  cvt_wext_kernel<<<(64 * 640 + 255) / 256, blk, 0, stream>>>(W1, root1, Bt1, 9);
  cvt_wext_kernel<<<(64 * 1664 + 255) / 256, blk, 0, stream>>>(W2, root2, Bt2, 25);

  // ----- layer 1 (K=3, K2=9, R=640) -----
  zbuild_kernel<3, 9><<<nbZ, blk, 0, stream>>>(eidx, row_start, src, attr, x, Z, N);
  gemm_fused_kernel<10><<<nbG, blk, 0, stream>>>(Z, Bt1, b1, h1, N);

  // ----- layer 2 (K=5, K2=25, R=1664) -----
  zbuild_kernel<5, 25><<<nbZ, blk, 0, stream>>>(eidx, row_start, src, attr, h1, Z, N);
  gemm_fused_kernel<26><<<nbG, blk, 0, stream>>>(Z, Bt2, b2, h2, N);

  // ----- MLP head -----
  node_dense_kernel<1><<<nb128, blk, 0, stream>>>(h2, m1w, m1b, t1, N);
  mlp2_kernel<<<(N + 31) / 32, blk, 0, stream>>>(t1, m2w, m2b, out, N);
}

// Round 6
// 484.388 us; speedup vs baseline: 5.0541x; 5.0541x over previous
//
#include <hip/hip_runtime.h>
#include <hip/hip_bf16.h>

typedef __attribute__((ext_vector_type(8))) short short8;
typedef __attribute__((ext_vector_type(4))) float floatx4;

__device__ __forceinline__ unsigned short f2bf(float x) {
  __hip_bfloat16 h = __float2bfloat16(x);
  return __builtin_bit_cast(unsigned short, h);
}

// ---------------------------------------------------------------------
// Build extended transposed weights: Bt[o][r], r = k*64+d for k<K2 (from
// W[k][d][o]), and r in [K2*64, K2*64+64) from root[d][o]. bf16.
// ---------------------------------------------------------------------
__global__ __launch_bounds__(256) void cvt_wext_kernel(
    const float* __restrict__ W, const float* __restrict__ root,
    unsigned short* __restrict__ Bt, int K2) {
  int R = (K2 + 1) * 64;
  int i = blockIdx.x * 256 + threadIdx.x;
  if (i >= 64 * R) return;
  int o = i / R, r = i - o * R;
  int k = r >> 6, d = r & 63;
  float v = (k < K2) ? W[(k << 12) + (d << 6) + o] : root[(d << 6) + o];
  Bt[(size_t)o * R + r] = f2bf(v);
}

// ---------------------------------------------------------------------
// CSR build: histogram -> scan -> cursor scatter
// ---------------------------------------------------------------------
__global__ __launch_bounds__(256) void zero_int_kernel(int* __restrict__ p, int n) {
  int i = blockIdx.x * 256 + threadIdx.x;
  if (i < n) p[i] = 0;
}

__global__ __launch_bounds__(256) void hist_kernel(
    const int* __restrict__ dst, int* __restrict__ deg, int nE) {
  int e = blockIdx.x * 256 + threadIdx.x;
  if (e < nE) atomicAdd(&deg[dst[e]], 1);
}

__global__ __launch_bounds__(256) void blocksum_kernel(
    const int* __restrict__ deg, int* __restrict__ partial, int N) {
  __shared__ int s[256];
  int t = threadIdx.x, i = blockIdx.x * 256 + t;
  s[t] = (i < N) ? deg[i] : 0;
  __syncthreads();
  for (int off = 128; off > 0; off >>= 1) {
    if (t < off) s[t] += s[t + off];
    __syncthreads();
  }
  if (t == 0) partial[blockIdx.x] = s[0];
}

// single-block exclusive scan of up to 256 partials (N <= 65536)
__global__ __launch_bounds__(256) void scanpartials_kernel(
    int* __restrict__ partial, int nb) {
  __shared__ int s[256];
  int t = threadIdx.x;
  int v = (t < nb) ? partial[t] : 0;
  s[t] = v;
  __syncthreads();
  for (int off = 1; off < 256; off <<= 1) {
    int x = (t >= off) ? s[t - off] : 0;
    __syncthreads();
    s[t] += x;
    __syncthreads();
  }
  if (t < nb) partial[t] = s[t] - v;
}

__global__ __launch_bounds__(256) void blockscan_kernel(
    const int* __restrict__ deg, const int* __restrict__ partial,
    int* __restrict__ row_start, int* __restrict__ cursor, int N, int nE) {
  __shared__ int s[256];
  int t = threadIdx.x, i = blockIdx.x * 256 + t;
  int v = (i < N) ? deg[i] : 0;
  s[t] = v;
  __syncthreads();
  for (int off = 1; off < 256; off <<= 1) {
    int x = (t >= off) ? s[t - off] : 0;
    __syncthreads();
    s[t] += x;
    __syncthreads();
  }
  if (i < N) {
    int excl = s[t] - v + partial[blockIdx.x];
    row_start[i] = excl;
    cursor[i] = excl;
  }
  if (i == 0) row_start[N] = nE;
}

__global__ __launch_bounds__(256) void scatter_kernel(
    const int* __restrict__ dst, int* __restrict__ cursor,
    int* __restrict__ eidx, int nE) {
  int e = blockIdx.x * 256 + threadIdx.x;
  if (e < nE) {
    int pos = atomicAdd(&cursor[dst[e]], 1);
    eidx[pos] = e;
  }
}

// ---------------------------------------------------------------------
// Z-build: one wave per dst node. Zext[n] = [ (1/deg)*bucketed x-sums , x[n] ]
// Bucket accum in PRIVATE-per-wave LDS with plain += (lane o owns column o;
// LDS ops are in program order per wave, so colliding buckets are safe).
// NO LDS atomics (atomic fadd on LDS lowers to a CAS waterfall — R4's 1095us
// pathology). Edge metadata staged 64-at-a-time; x-row gather pipelined 2 deep.
// ---------------------------------------------------------------------
template <int K, int K2>
__global__ __launch_bounds__(256) void zbuild_kernel(
    const int* __restrict__ eidx, const int* __restrict__ row_start,
    const int* __restrict__ src, const float* __restrict__ attr,
    const float* __restrict__ X, unsigned short* __restrict__ Z, int N) {
  constexpr int R = (K2 + 1) * 64;
  __shared__ float Zacc[4][K2 * 64];
  __shared__ float metaB[4][64][4];
  __shared__ int metaS[4][64];
  __shared__ int metaK[4][64];
  const int t = threadIdx.x, w = t >> 6, o = t & 63;
  const int node = blockIdx.x * 4 + w;
  if (node >= N) return;  // no __syncthreads anywhere in this kernel

  float* za = Zacc[w];
#pragma unroll
  for (int k = 0; k < K2; ++k) za[k * 64 + o] = 0.f;

  const int beg = row_start[node], end = row_start[node + 1];
  for (int c0 = beg; c0 < end; c0 += 64) {
    const int m = min(64, end - c0);
    if (o < m) {
      int e = eidx[c0 + o];
      float2 a = *(const float2*)&attr[2 * e];
      int s = src[e];
      float u = a.x * (float)(K - 1);
      float v = a.y * (float)(K - 1);
      float lf0 = floorf(u), lf1 = floorf(v);
      float f0 = u - lf0, f1 = v - lf1;
      int l0 = (int)lf0, l1 = (int)lf1;
      int i00 = min(max(l0, 0), K - 1), i01 = min(max(l0 + 1, 0), K - 1);
      int i10 = min(max(l1, 0), K - 1), i11 = min(max(l1 + 1, 0), K - 1);
      metaB[w][o][0] = (1.f - f0) * (1.f - f1);
      metaB[w][o][1] = (1.f - f0) * f1;
      metaB[w][o][2] = f0 * (1.f - f1);
      metaB[w][o][3] = f0 * f1;
      metaS[w][o] = s;
      metaK[w][o] = (i00 + i10 * K) | ((i00 + i11 * K) << 8) |
                    ((i01 + i10 * K) << 16) | ((i01 + i11 * K) << 24);
    }
    // same-wave LDS write->read: lockstep + compiler waitcnts keep this safe
    float xv0 = (m > 0) ? X[(size_t)metaS[w][0] * 64 + o] : 0.f;
    float xv1 = (m > 1) ? X[(size_t)metaS[w][1] * 64 + o] : 0.f;
    for (int j = 0; j < m; ++j) {
      float xn = 0.f;
      if (j + 2 < m) {
        int sn = metaS[w][j + 2];
        xn = X[(size_t)sn * 64 + o];
      }
      int kp = metaK[w][j];
      float4 b = *(const float4*)&metaB[w][j][0];
      za[(kp & 255) * 64 + o]         += b.x * xv0;
      za[((kp >> 8) & 255) * 64 + o]  += b.y * xv0;
      za[((kp >> 16) & 255) * 64 + o] += b.z * xv0;
      za[((kp >> 24) & 255) * 64 + o] += b.w * xv0;
      xv0 = xv1;
      xv1 = xn;
    }
  }

  const int deg = end - beg;
  const float inv = 1.f / (float)max(deg, 1);
  unsigned short* zr = Z + (size_t)node * R;
#pragma unroll
  for (int k = 0; k < K2; ++k) zr[k * 64 + o] = f2bf(za[k * 64 + o] * inv);
  zr[K2 * 64 + o] = f2bf(X[(size_t)node * 64 + o]);
}

// ---------------------------------------------------------------------
// Fused GEMM: out[n,o] = ELU( Zext[n,:] @ Bt[o,:] + bias[o] )  (bf16 MFMA)
// Zext row-major [N x R], Bt row-major [64 x R], R = KC*64.
// ---------------------------------------------------------------------
template <int KC>
__global__ __launch_bounds__(256) void gemm_fused_kernel(
    const unsigned short* __restrict__ Z, const unsigned short* __restrict__ Bt,
    const float* __restrict__ bias, float* __restrict__ out, int N) {
  constexpr int R = KC * 64;
  __shared__ unsigned short As[64 * 72];
  __shared__ unsigned short Bs[64 * 72];
  const int t = threadIdx.x, w = t >> 6, lane = t & 63;
  const int mrow = lane & 15, q = lane >> 4;
  const int n0 = blockIdx.x * 64;

  floatx4 acc[4] = {{0,0,0,0},{0,0,0,0},{0,0,0,0},{0,0,0,0}};

  for (int kc = 0; kc < KC; ++kc) {
    __syncthreads();
    for (int i = t; i < 512; i += 256) {
      int row = i >> 3, cg = i & 7;
      int n = n0 + row;
      float4 val = make_float4(0.f, 0.f, 0.f, 0.f);
      if (n < N) val = *(const float4*)&Z[(size_t)n * R + kc * 64 + cg * 8];
      *(float4*)&As[row * 72 + cg * 8] = val;
    }
    for (int i = t; i < 512; i += 256) {
      int row = i >> 3, cg = i & 7;
      *(float4*)&Bs[row * 72 + cg * 8] =
          *(const float4*)&Bt[(size_t)row * R + kc * 64 + cg * 8];
    }
    __syncthreads();

    short8 a0 = *(const short8*)&As[(w * 16 + mrow) * 72 + q * 8];
    short8 a1 = *(const short8*)&As[(w * 16 + mrow) * 72 + 32 + q * 8];
#pragma unroll
    for (int ot = 0; ot < 4; ++ot) {
      short8 b0 = *(const short8*)&Bs[(ot * 16 + mrow) * 72 + q * 8];
      short8 b1 = *(const short8*)&Bs[(ot * 16 + mrow) * 72 + 32 + q * 8];
      acc[ot] = __builtin_amdgcn_mfma_f32_16x16x32_bf16(a0, b0, acc[ot], 0, 0, 0);
      acc[ot] = __builtin_amdgcn_mfma_f32_16x16x32_bf16(a1, b1, acc[ot], 0, 0, 0);
    }
  }

  // epilogue: D layout col(o)=ot*16+mrow, row(node)=q*4+r
#pragma unroll
  for (int ot = 0; ot < 4; ++ot) {
    float b = bias[ot * 16 + mrow];
#pragma unroll
    for (int r = 0; r < 4; ++r) {
      int node = n0 + w * 16 + q * 4 + r;
      if (node < N) {
        float v = acc[ot][r] + b;
        v = v > 0.f ? v : (expf(v) - 1.f);
        out[(size_t)node * 64 + ot * 16 + mrow] = v;
      }
    }
  }
}

// ---------------------------------------------------------------------
// dense layer (fp32 VALU): out = act(X@Wm + b); ACT 1=ReLU
// ---------------------------------------------------------------------
template <int ACT>
__global__ __launch_bounds__(256) void node_dense_kernel(
    const float* __restrict__ X, const float* __restrict__ Wm,
    const float* __restrict__ bias, float* __restrict__ out, int N) {
  __shared__ float Ws[64 * 64];
  __shared__ float XsT[64 * 132];
  const int t = threadIdx.x;
  const int n0 = blockIdx.x * 128;

  for (int i = t; i < 1024; i += 256)
    ((float4*)Ws)[i] = ((const float4*)Wm)[i];
  for (int i = t; i < 8192; i += 256) {
    int nl = i >> 6, d = i & 63;
    int n = n0 + nl;
    XsT[d * 132 + nl] = (n < N) ? X[(size_t)n * 64 + d] : 0.f;
  }
  __syncthreads();

  const int o = t & 63, ng = t >> 6;
  float acc[32];
#pragma unroll
  for (int j = 0; j < 32; ++j) acc[j] = 0.f;

  for (int d = 0; d < 64; ++d) {
    float w = Ws[d * 64 + o];
    const float4* xp = (const float4*)&XsT[d * 132 + ng * 32];
#pragma unroll
    for (int j4 = 0; j4 < 8; ++j4) {
      float4 xv = xp[j4];
      acc[j4 * 4 + 0] += xv.x * w;
      acc[j4 * 4 + 1] += xv.y * w;
      acc[j4 * 4 + 2] += xv.z * w;
      acc[j4 * 4 + 3] += xv.w * w;
    }
  }

  float b = bias[o];
#pragma unroll
  for (int j = 0; j < 32; ++j) {
    int n = n0 + ng * 32 + j;
    if (n >= N) continue;
    float v = acc[j] + b;
    if (ACT == 0) v = v > 0.f ? v : (expf(v) - 1.f);
    else          v = v > 0.f ? v : 0.f;
    out[(size_t)n * 64 + o] = v;
  }
}

// ---------------------------------------------------------------------
// final projection D=64 -> C=8 with ReLU
// ---------------------------------------------------------------------
__global__ __launch_bounds__(256) void mlp2_kernel(
    const float* __restrict__ X, const float* __restrict__ W,
    const float* __restrict__ bias, float* __restrict__ out, int N) {
  __shared__ float Ws[512];
  __shared__ float bs[8];
  __shared__ float Xs[32 * 64];
  int t = threadIdx.x;
  int n0 = blockIdx.x * 32;
  if (t < 8) bs[t] = bias[t];
  for (int i = t; i < 512; i += 256) Ws[i] = W[i];
  for (int i = t; i < 512; i += 256) {
    int n = n0 + (i >> 4);
    ((float4*)Xs)[i] = (n < N) ? ((const float4*)(X + (size_t)n * 64))[i & 15]
                               : make_float4(0.f, 0.f, 0.f, 0.f);
  }
  __syncthreads();
  int c = t & 7, nl = t >> 3;
  float acc = bs[c];
  for (int d = 0; d < 64; ++d) acc += Xs[nl * 64 + d] * Ws[d * 8 + c];
  int n = n0 + nl;
  if (n < N) out[(size_t)n * 8 + c] = acc > 0.f ? acc : 0.f;
}

// ---------------------------------------------------------------------
extern "C" void kernel_launch(void* const* d_in, const int* in_sizes, int n_in,
                              void* d_out, int out_size, void* d_ws, size_t ws_size,
                              hipStream_t stream) {
  const float* x     = (const float*)d_in[0];
  const int*   ei    = (const int*)d_in[1];
  const float* attr  = (const float*)d_in[2];
  const float* W1    = (const float*)d_in[3];
  const float* root1 = (const float*)d_in[4];
  const float* b1    = (const float*)d_in[5];
  const float* W2    = (const float*)d_in[6];
  const float* root2 = (const float*)d_in[7];
  const float* b2    = (const float*)d_in[8];
  const float* m1w   = (const float*)d_in[9];
  const float* m1b   = (const float*)d_in[10];
  const float* m2w   = (const float*)d_in[11];
  const float* m2b   = (const float*)d_in[12];

  const int N  = in_sizes[0] / 64;
  const int nE = in_sizes[1] / 2;
  const int* src  = ei;
  const int* dstv = ei + nE;
  float* out = (float*)d_out;

  // workspace layout
  float* h1 = (float*)d_ws;                 // N*64
  float* h2 = h1 + (size_t)N * 64;          // N*64
  float* t1 = h2 + (size_t)N * 64;          // N*64
  int* deg       = (int*)(t1 + (size_t)N * 64);
  int* row_start = deg + N;
  int* cursor    = row_start + (N + 1);
  int* eidx      = cursor + N;
  int* partial   = eidx + nE;               // 256
  char* pbase = (char*)(partial + 256);
  pbase = (char*)(((uintptr_t)pbase + 15) & ~(uintptr_t)15);
  unsigned short* Bt1 = (unsigned short*)pbase;       // 64 * 640
  unsigned short* Bt2 = Bt1 + 64 * 640;               // 64 * 1664
  unsigned short* Z   = Bt2 + 64 * 1664;              // N * 1664

  dim3 blk(256);
  int nbN  = (N + 255) / 256;
  int nbE  = (nE + 255) / 256;
  int nbZ  = (N + 3) / 4;
  int nbG  = (N + 63) / 64;
  int nb128 = (N + 127) / 128;

  // ----- CSR build (graph identical both layers) -----
  zero_int_kernel<<<nbN, blk, 0, stream>>>(deg, N);
  hist_kernel<<<nbE, blk, 0, stream>>>(dstv, deg, nE);
  blocksum_kernel<<<nbN, blk, 0, stream>>>(deg, partial, N);
  scanpartials_kernel<<<1, blk, 0, stream>>>(partial, nbN);
  blockscan_kernel<<<nbN, blk, 0, stream>>>(deg, partial, row_start, cursor, N, nE);
  scatter_kernel<<<nbE, blk, 0, stream>>>(dstv, cursor, eidx, nE);

  // ----- weight prep -----
  cvt_wext_kernel<<<(64 * 640 + 255) / 256, blk, 0, stream>>>(W1, root1, Bt1, 9);
  cvt_wext_kernel<<<(64 * 1664 + 255) / 256, blk, 0, stream>>>(W2, root2, Bt2, 25);

  // ----- layer 1 (K=3, K2=9, R=640) -----
  zbuild_kernel<3, 9><<<nbZ, blk, 0, stream>>>(eidx, row_start, src, attr, x, Z, N);
  gemm_fused_kernel<10><<<nbG, blk, 0, stream>>>(Z, Bt1, b1, h1, N);

  // ----- layer 2 (K=5, K2=25, R=1664) -----
  zbuild_kernel<5, 25><<<nbZ, blk, 0, stream>>>(eidx, row_start, src, attr, h1, Z, N);
  gemm_fused_kernel<26><<<nbG, blk, 0, stream>>>(Z, Bt2, b2, h2, N);

  // ----- MLP head -----
  node_dense_kernel<1><<<nb128, blk, 0, stream>>>(h2, m1w, m1b, t1, N);
  mlp2_kernel<<<(N + 31) / 32, blk, 0, stream>>>(t1, m2w, m2b, out, N);
}

// Round 7
// 471.159 us; speedup vs baseline: 5.1960x; 1.0281x over previous
//
#include <hip/hip_runtime.h>
#include <hip/hip_bf16.h>

typedef __attribute__((ext_vector_type(8))) short short8;
typedef __attribute__((ext_vector_type(4))) float floatx4;

__device__ __forceinline__ unsigned short f2bf(float x) {
  __hip_bfloat16 h = __float2bfloat16(x);
  return __builtin_bit_cast(unsigned short, h);
}

// ---------------------------------------------------------------------
// Build extended transposed weights: Bt[o][r], r = k*64+d for k<K2 (from
// W[k][d][o]), and r in [K2*64, K2*64+64) from root[d][o]. bf16.
// ---------------------------------------------------------------------
__global__ __launch_bounds__(256) void cvt_wext_kernel(
    const float* __restrict__ W, const float* __restrict__ root,
    unsigned short* __restrict__ Bt, int K2) {
  int R = (K2 + 1) * 64;
  int i = blockIdx.x * 256 + threadIdx.x;
  if (i >= 64 * R) return;
  int o = i / R, r = i - o * R;
  int k = r >> 6, d = r & 63;
  float v = (k < K2) ? W[(k << 12) + (d << 6) + o] : root[(d << 6) + o];
  Bt[(size_t)o * R + r] = f2bf(v);
}

// ---------------------------------------------------------------------
// CSR build: histogram -> scan -> cursor scatter
// ---------------------------------------------------------------------
__global__ __launch_bounds__(256) void zero_int_kernel(int* __restrict__ p, int n) {
  int i = blockIdx.x * 256 + threadIdx.x;
  if (i < n) p[i] = 0;
}

__global__ __launch_bounds__(256) void hist_kernel(
    const int* __restrict__ dst, int* __restrict__ deg, int nE) {
  int e = blockIdx.x * 256 + threadIdx.x;
  if (e < nE) atomicAdd(&deg[dst[e]], 1);
}

__global__ __launch_bounds__(256) void blocksum_kernel(
    const int* __restrict__ deg, int* __restrict__ partial, int N) {
  __shared__ int s[256];
  int t = threadIdx.x, i = blockIdx.x * 256 + t;
  s[t] = (i < N) ? deg[i] : 0;
  __syncthreads();
  for (int off = 128; off > 0; off >>= 1) {
    if (t < off) s[t] += s[t + off];
    __syncthreads();
  }
  if (t == 0) partial[blockIdx.x] = s[0];
}

// single-block exclusive scan of up to 256 partials (N <= 65536)
__global__ __launch_bounds__(256) void scanpartials_kernel(
    int* __restrict__ partial, int nb) {
  __shared__ int s[256];
  int t = threadIdx.x;
  int v = (t < nb) ? partial[t] : 0;
  s[t] = v;
  __syncthreads();
  for (int off = 1; off < 256; off <<= 1) {
    int x = (t >= off) ? s[t - off] : 0;
    __syncthreads();
    s[t] += x;
    __syncthreads();
  }
  if (t < nb) partial[t] = s[t] - v;
}

__global__ __launch_bounds__(256) void blockscan_kernel(
    const int* __restrict__ deg, const int* __restrict__ partial,
    int* __restrict__ row_start, int* __restrict__ cursor, int N, int nE) {
  __shared__ int s[256];
  int t = threadIdx.x, i = blockIdx.x * 256 + t;
  int v = (i < N) ? deg[i] : 0;
  s[t] = v;
  __syncthreads();
  for (int off = 1; off < 256; off <<= 1) {
    int x = (t >= off) ? s[t - off] : 0;
    __syncthreads();
    s[t] += x;
    __syncthreads();
  }
  if (i < N) {
    int excl = s[t] - v + partial[blockIdx.x];
    row_start[i] = excl;
    cursor[i] = excl;
  }
  if (i == 0) row_start[N] = nE;
}

__global__ __launch_bounds__(256) void scatter_kernel(
    const int* __restrict__ dst, int* __restrict__ cursor,
    int* __restrict__ eidx, int nE) {
  int e = blockIdx.x * 256 + threadIdx.x;
  if (e < nE) {
    int pos = atomicAdd(&cursor[dst[e]], 1);
    eidx[pos] = e;
  }
}

// ---------------------------------------------------------------------
// Z-build: one wave per dst node. Zext[n] = [ (1/deg)*bucketed x-sums , x[n] ]
// Bucket accum in private-per-wave LDS, plain += (lane o owns column o).
// Bilinear structure: the 4 bucket updates form two pairs with CONSTANT
// 64-dword LDS delta (k0, k0+1) -> compiler merges each pair into
// ds_read2_b32/ds_write2_b32, halving LDS instructions per edge.
// Clamp cases folded into coefficients at staging (slot2 coeff = 0);
// one spare za row keeps the k0+1 slot in-bounds. x-gather pipelined 3 deep.
// ---------------------------------------------------------------------
template <int K, int K2>
__global__ __launch_bounds__(256) void zbuild_kernel(
    const int* __restrict__ eidx, const int* __restrict__ row_start,
    const int* __restrict__ src, const float* __restrict__ attr,
    const float* __restrict__ X, unsigned short* __restrict__ Z, int N) {
  constexpr int R = (K2 + 1) * 64;
  __shared__ float Zacc[4][(K2 + 1) * 64];   // +1 spare row (clamp safety)
  __shared__ float metaB[4][64][4];
  __shared__ int metaS[4][64];
  __shared__ int metaK[4][64];
  const int t = threadIdx.x, w = t >> 6, o = t & 63;
  const int node = blockIdx.x * 4 + w;
  if (node >= N) return;  // no __syncthreads anywhere in this kernel

  float* za = Zacc[w];
#pragma unroll
  for (int k = 0; k < K2; ++k) za[k * 64 + o] = 0.f;

  const int beg = row_start[node], end = row_start[node + 1];
  for (int c0 = beg; c0 < end; c0 += 64) {
    const int m = min(64, end - c0);
    if (o < m) {
      int e = eidx[c0 + o];
      float2 a = *(const float2*)&attr[2 * e];
      int s = src[e];
      float u = a.x * (float)(K - 1);
      float v = a.y * (float)(K - 1);
      float lf0 = floorf(u), lf1 = floorf(v);
      float f0 = u - lf0, f1 = v - lf1;
      int l0 = (int)lf0, l1 = (int)lf1;
      int i00 = min(max(l0, 0), K - 1), i01 = min(max(l0 + 1, 0), K - 1);
      int i10 = min(max(l1, 0), K - 1), i11 = min(max(l1 + 1, 0), K - 1);
      float w00 = (1.f - f0) * (1.f - f1);   // (i00, i10)
      float w01 = (1.f - f0) * f1;           // (i00, i11)
      float w10 = f0 * (1.f - f1);           // (i01, i10)
      float w11 = f0 * f1;                   // (i01, i11)
      int du = i01 - i00;                    // 1 for uniform [0,1) attr
      // pair A at i1=i10: slots (k0, k0+1); pair B at i1=i11: (kB, kB+1)
      metaB[w][o][0] = du ? w00 : (w00 + w10);
      metaB[w][o][1] = du ? w10 : 0.f;
      metaB[w][o][2] = du ? w01 : (w01 + w11);
      metaB[w][o][3] = du ? w11 : 0.f;
      int k0 = i00 + i10 * K;
      int kB = i00 + i11 * K;   // dv==0 -> kB==k0; in-order LDS keeps it exact
      metaS[w][o] = s;
      metaK[w][o] = k0 | (kB << 8);
    }
    // same-wave LDS write->read: lockstep + compiler waitcnts keep this safe
    float xv0 = (m > 0) ? X[(size_t)metaS[w][0] * 64 + o] : 0.f;
    float xv1 = (m > 1) ? X[(size_t)metaS[w][1] * 64 + o] : 0.f;
    float xv2 = (m > 2) ? X[(size_t)metaS[w][2] * 64 + o] : 0.f;
    for (int j = 0; j < m; ++j) {
      float xn = 0.f;
      if (j + 3 < m) {
        int sn = metaS[w][j + 3];
        xn = X[(size_t)sn * 64 + o];
      }
      int kp = metaK[w][j];
      float4 b = *(const float4*)&metaB[w][j][0];
      float* pA = &za[(kp & 255) * 64 + o];
      float* pB = &za[((kp >> 8) & 255) * 64 + o];
      // constant 64-dword delta -> ds_read2_b32 / ds_write2_b32
      float a0 = pA[0] + b.x * xv0;
      float a1 = pA[64] + b.y * xv0;
      pA[0] = a0;
      pA[64] = a1;
      float b0 = pB[0] + b.z * xv0;
      float b1 = pB[64] + b.w * xv0;
      pB[0] = b0;
      pB[64] = b1;
      xv0 = xv1; xv1 = xv2; xv2 = xn;
    }
  }

  const int deg = end - beg;
  const float inv = 1.f / (float)max(deg, 1);
  unsigned short* zr = Z + (size_t)node * R;
#pragma unroll
  for (int k = 0; k < K2; ++k) zr[k * 64 + o] = f2bf(za[k * 64 + o] * inv);
  zr[K2 * 64 + o] = f2bf(X[(size_t)node * 64 + o]);
}

// ---------------------------------------------------------------------
// Fused GEMM: out[n,o] = ELU( Zext[n,:] @ Bt[o,:] + bias[o] )  (bf16 MFMA)
// Zext row-major [N x R], Bt row-major [64 x R], R = KC*64.
// ---------------------------------------------------------------------
template <int KC>
__global__ __launch_bounds__(256) void gemm_fused_kernel(
    const unsigned short* __restrict__ Z, const unsigned short* __restrict__ Bt,
    const float* __restrict__ bias, float* __restrict__ out, int N) {
  constexpr int R = KC * 64;
  __shared__ unsigned short As[64 * 72];
  __shared__ unsigned short Bs[64 * 72];
  const int t = threadIdx.x, w = t >> 6, lane = t & 63;
  const int mrow = lane & 15, q = lane >> 4;
  const int n0 = blockIdx.x * 64;

  floatx4 acc[4] = {{0,0,0,0},{0,0,0,0},{0,0,0,0},{0,0,0,0}};

  for (int kc = 0; kc < KC; ++kc) {
    __syncthreads();
    for (int i = t; i < 512; i += 256) {
      int row = i >> 3, cg = i & 7;
      int n = n0 + row;
      float4 val = make_float4(0.f, 0.f, 0.f, 0.f);
      if (n < N) val = *(const float4*)&Z[(size_t)n * R + kc * 64 + cg * 8];
      *(float4*)&As[row * 72 + cg * 8] = val;
    }
    for (int i = t; i < 512; i += 256) {
      int row = i >> 3, cg = i & 7;
      *(float4*)&Bs[row * 72 + cg * 8] =
          *(const float4*)&Bt[(size_t)row * R + kc * 64 + cg * 8];
    }
    __syncthreads();

    short8 a0 = *(const short8*)&As[(w * 16 + mrow) * 72 + q * 8];
    short8 a1 = *(const short8*)&As[(w * 16 + mrow) * 72 + 32 + q * 8];
#pragma unroll
    for (int ot = 0; ot < 4; ++ot) {
      short8 b0 = *(const short8*)&Bs[(ot * 16 + mrow) * 72 + q * 8];
      short8 b1 = *(const short8*)&Bs[(ot * 16 + mrow) * 72 + 32 + q * 8];
      acc[ot] = __builtin_amdgcn_mfma_f32_16x16x32_bf16(a0, b0, acc[ot], 0, 0, 0);
      acc[ot] = __builtin_amdgcn_mfma_f32_16x16x32_bf16(a1, b1, acc[ot], 0, 0, 0);
    }
  }

  // epilogue: D layout col(o)=ot*16+mrow, row(node)=q*4+r
#pragma unroll
  for (int ot = 0; ot < 4; ++ot) {
    float b = bias[ot * 16 + mrow];
#pragma unroll
    for (int r = 0; r < 4; ++r) {
      int node = n0 + w * 16 + q * 4 + r;
      if (node < N) {
        float v = acc[ot][r] + b;
        v = v > 0.f ? v : (expf(v) - 1.f);
        out[(size_t)node * 64 + ot * 16 + mrow] = v;
      }
    }
  }
}

// ---------------------------------------------------------------------
// dense layer (fp32 VALU): out = act(X@Wm + b); ACT 1=ReLU
// ---------------------------------------------------------------------
template <int ACT>
__global__ __launch_bounds__(256) void node_dense_kernel(
    const float* __restrict__ X, const float* __restrict__ Wm,
    const float* __restrict__ bias, float* __restrict__ out, int N) {
  __shared__ float Ws[64 * 64];
  __shared__ float XsT[64 * 132];
  const int t = threadIdx.x;
  const int n0 = blockIdx.x * 128;

  for (int i = t; i < 1024; i += 256)
    ((float4*)Ws)[i] = ((const float4*)Wm)[i];
  for (int i = t; i < 8192; i += 256) {
    int nl = i >> 6, d = i & 63;
    int n = n0 + nl;
    XsT[d * 132 + nl] = (n < N) ? X[(size_t)n * 64 + d] : 0.f;
  }
  __syncthreads();

  const int o = t & 63, ng = t >> 6;
  float acc[32];
#pragma unroll
  for (int j = 0; j < 32; ++j) acc[j] = 0.f;

  for (int d = 0; d < 64; ++d) {
    float w = Ws[d * 64 + o];
    const float4* xp = (const float4*)&XsT[d * 132 + ng * 32];
#pragma unroll
    for (int j4 = 0; j4 < 8; ++j4) {
      float4 xv = xp[j4];
      acc[j4 * 4 + 0] += xv.x * w;
      acc[j4 * 4 + 1] += xv.y * w;
      acc[j4 * 4 + 2] += xv.z * w;
      acc[j4 * 4 + 3] += xv.w * w;
    }
  }

  float b = bias[o];
#pragma unroll
  for (int j = 0; j < 32; ++j) {
    int n = n0 + ng * 32 + j;
    if (n >= N) continue;
    float v = acc[j] + b;
    if (ACT == 0) v = v > 0.f ? v : (expf(v) - 1.f);
    else          v = v > 0.f ? v : 0.f;
    out[(size_t)n * 64 + o] = v;
  }
}

// ---------------------------------------------------------------------
// final projection D=64 -> C=8 with ReLU
// ---------------------------------------------------------------------
__global__ __launch_bounds__(256) void mlp2_kernel(
    const float* __restrict__ X, const float* __restrict__ W,
    const float* __restrict__ bias, float* __restrict__ out, int N) {
  __shared__ float Ws[512];
  __shared__ float bs[8];
  __shared__ float Xs[32 * 64];
  int t = threadIdx.x;
  int n0 = blockIdx.x * 32;
  if (t < 8) bs[t] = bias[t];
  for (int i = t; i < 512; i += 256) Ws[i] = W[i];
  for (int i = t; i < 512; i += 256) {
    int n = n0 + (i >> 4);
    ((float4*)Xs)[i] = (n < N) ? ((const float4*)(X + (size_t)n * 64))[i & 15]
                               : make_float4(0.f, 0.f, 0.f, 0.f);
  }
  __syncthreads();
  int c = t & 7, nl = t >> 3;
  float acc = bs[c];
  for (int d = 0; d < 64; ++d) acc += Xs[nl * 64 + d] * Ws[d * 8 + c];
  int n = n0 + nl;
  if (n < N) out[(size_t)n * 8 + c] = acc > 0.f ? acc : 0.f;
}

// ---------------------------------------------------------------------
extern "C" void kernel_launch(void* const* d_in, const int* in_sizes, int n_in,
                              void* d_out, int out_size, void* d_ws, size_t ws_size,
                              hipStream_t stream) {
  const float* x     = (const float*)d_in[0];
  const int*   ei    = (const int*)d_in[1];
  const float* attr  = (const float*)d_in[2];
  const float* W1    = (const float*)d_in[3];
  const float* root1 = (const float*)d_in[4];
  const float* b1    = (const float*)d_in[5];
  const float* W2    = (const float*)d_in[6];
  const float* root2 = (const float*)d_in[7];
  const float* b2    = (const float*)d_in[8];
  const float* m1w   = (const float*)d_in[9];
  const float* m1b   = (const float*)d_in[10];
  const float* m2w   = (const float*)d_in[11];
  const float* m2b   = (const float*)d_in[12];

  const int N  = in_sizes[0] / 64;
  const int nE = in_sizes[1] / 2;
  const int* src  = ei;
  const int* dstv = ei + nE;
  float* out = (float*)d_out;

  // workspace layout
  float* h1 = (float*)d_ws;                 // N*64
  float* h2 = h1 + (size_t)N * 64;          // N*64
  float* t1 = h2 + (size_t)N * 64;          // N*64
  int* deg       = (int*)(t1 + (size_t)N * 64);
  int* row_start = deg + N;
  int* cursor    = row_start + (N + 1);
  int* eidx      = cursor + N;
  int* partial   = eidx + nE;               // 256
  char* pbase = (char*)(partial + 256);
  pbase = (char*)(((uintptr_t)pbase + 15) & ~(uintptr_t)15);
  unsigned short* Bt1 = (unsigned short*)pbase;       // 64 * 640
  unsigned short* Bt2 = Bt1 + 64 * 640;               // 64 * 1664
  unsigned short* Z   = Bt2 + 64 * 1664;              // N * 1664

  dim3 blk(256);
  int nbN  = (N + 255) / 256;
  int nbE  = (nE + 255) / 256;
  int nbZ  = (N + 3) / 4;
  int nbG  = (N + 63) / 64;
  int nb128 = (N + 127) / 128;

  // ----- CSR build (graph identical both layers) -----
  zero_int_kernel<<<nbN, blk, 0, stream>>>(deg, N);
  hist_kernel<<<nbE, blk, 0, stream>>>(dstv, deg, nE);
  blocksum_kernel<<<nbN, blk, 0, stream>>>(deg, partial, N);
  scanpartials_kernel<<<1, blk, 0, stream>>>(partial, nbN);
  blockscan_kernel<<<nbN, blk, 0, stream>>>(deg, partial, row_start, cursor, N, nE);
  scatter_kernel<<<nbE, blk, 0, stream>>>(dstv, cursor, eidx, nE);

  // ----- weight prep -----
  cvt_wext_kernel<<<(64 * 640 + 255) / 256, blk, 0, stream>>>(W1, root1, Bt1, 9);
  cvt_wext_kernel<<<(64 * 1664 + 255) / 256, blk, 0, stream>>>(W2, root2, Bt2, 25);

  // ----- layer 1 (K=3, K2=9, R=640) -----
  zbuild_kernel<3, 9><<<nbZ, blk, 0, stream>>>(eidx, row_start, src, attr, x, Z, N);
  gemm_fused_kernel<10><<<nbG, blk, 0, stream>>>(Z, Bt1, b1, h1, N);

  // ----- layer 2 (K=5, K2=25, R=1664) -----
  zbuild_kernel<5, 25><<<nbZ, blk, 0, stream>>>(eidx, row_start, src, attr, h1, Z, N);
  gemm_fused_kernel<26><<<nbG, blk, 0, stream>>>(Z, Bt2, b2, h2, N);

  // ----- MLP head -----
  node_dense_kernel<1><<<nb128, blk, 0, stream>>>(h2, m1w, m1b, t1, N);
  mlp2_kernel<<<(N + 31) / 32, blk, 0, stream>>>(t1, m2w, m2b, out, N);
}